// Round 5
// baseline (380.481 us; speedup 1.0000x reference)
//
#include <hip/hip_runtime.h>
#include <math.h>

#define EPS 1e-6f
#define LN_EPS 1e-5f

typedef __attribute__((ext_vector_type(8))) short bf16x8;
typedef __attribute__((ext_vector_type(4))) float f32x4;

// ---------------- workspace layout (bytes) ----------------
#define SD_OFF    0ULL
#define SD_SZ     (1024ULL*60*128*4)
#define BP_OFF    SD_OFF                    // [B*W*C][8] band powers + alpha feats
#define BTH_OFF   (SD_OFF + 4ULL*1024*1024) // FBh fragment-ordered twiddles (64KB)
#define BTL_OFF   (BTH_OFF + 65536ULL)      // FBl (64KB)
#define FEAT_OFF  (SD_OFF + SD_SZ)
#define FEAT_SZ   (60416ULL*16*4)
#define W1H_OFF   (FEAT_OFF + FEAT_SZ)      // Wf1 fragment-ordered hi (32KB)
#define W1L_OFF   (W1H_OFF + 32768ULL)      // lo (32KB)
#define WT_OFF    (W1L_OFF + 32768ULL)
#define WT_SZ     (512ULL*512*2)
#define DSC_OFF   (WT_OFF + WT_SZ)
#define DSC_SZ    (944ULL*16*4)
#define MSK_OFF   (DSC_OFF + DSC_SZ)
#define MSK_SZ    (1024ULL*4)
#define REG_OFF   (MSK_OFF + MSK_SZ)
#define REG_SZ    (4096ULL*4)
#define CNT_OFF   (REG_OFF + REG_SZ)
#define CNT_SZ    (64ULL*4)
#define SUP_OFF   (CNT_OFF + CNT_SZ)

#define TOKENS_N  30932992ULL               // 16*59*64*512

__device__ inline unsigned short f2bf(float f) {
  union { float f; unsigned u; } v; v.f = f;
  unsigned u = v.u;
  return (unsigned short)((u + 0x7fffu + ((u >> 16) & 1u)) >> 16);  // RNE
}

__device__ inline void gload16(const void* g, void* l) {
  __builtin_amdgcn_global_load_lds((const __attribute__((address_space(1))) unsigned int*)g,
                                   (__attribute__((address_space(3))) unsigned int*)l, 16, 0, 0);
}

// exact-GELU via Abramowitz-Stegun 7.1.26 erf (|err|<1.5e-7 << bf16 eps)
__device__ inline float gelu_f(float z) {
  float s = z * 0.70710678118654752f;
  float a = fabsf(s);
  float t = __builtin_amdgcn_rcpf(fmaf(0.3275911f, a, 1.f));
  float p = t*(0.254829592f + t*(-0.284496736f + t*(1.421413741f + t*(-1.453152027f + t*1.061405429f))));
  float e = __expf(-a*a);
  float er = copysignf(fmaf(-p, e, 1.f), s);
  return 0.5f * z * (1.f + er);
}

// ---------------- kernel: setup ----------------
__global__ __launch_bounds__(1024) void k_setup(const void* mraw, const float* spos,
    float* maskf, float* regm, float* cnts, float* sup) {
  __shared__ int okint, okflt;
  __shared__ int anyr[4];
  __shared__ float cbuf[4][16];
  int t = threadIdx.x;
  if (t == 0) { okint = 1; okflt = 1; }
  if (t < 4) anyr[t] = 0;
  if (t < 64) cbuf[t>>4][t&15] = 0.f;
  __syncthreads();
  if (t < 256) {
    unsigned v = ((const unsigned*)mraw)[t];
    if (v > 1u) okint = 0;
    if (v != 0u && v != 0x3f800000u) okflt = 0;
  }
  __syncthreads();
  float mv;
  if (okint)      mv = (float)((const int*)mraw)[t];
  else if (okflt) mv = ((const float*)mraw)[t];
  else            mv = (float)((const unsigned char*)mraw)[t];
  maskf[t] = mv;
  bool mk = mv > 0.5f;
  float px = spos[2*t], py = spos[2*t+1];
  int lm = ((px < -0.02f) && mk) ? 1 : 0;
  int rm = ((px >  0.02f) && mk) ? 1 : 0;
  int pm = ((py < -0.02f) && mk) ? 1 : 0;
  int am = ((py >  0.02f) && mk) ? 1 : 0;
  if (lm) anyr[0] = 1;
  if (rm) anyr[1] = 1;
  if (pm) anyr[2] = 1;
  if (am) anyr[3] = 1;
  __syncthreads();
  float lv = anyr[0] ? (float)lm : 0.f;
  float rv = anyr[1] ? (float)rm : 0.f;
  float pv = anyr[2] ? (float)pm : 1.f;   // posterior fallback = True
  float av = anyr[3] ? (float)am : 0.f;
  regm[t] = lv; regm[1024+t] = rv; regm[2048+t] = pv; regm[3072+t] = av;
  int b = t >> 6;
  atomicAdd(&cbuf[0][b], lv);
  atomicAdd(&cbuf[1][b], rv);
  atomicAdd(&cbuf[2][b], pv);
  atomicAdd(&cbuf[3][b], av);
  __syncthreads();
  if (t < 64) cnts[t] = cbuf[t>>4][t&15];
  if (t < 16) sup[t] = (cbuf[3][t] > 0.f && cbuf[2][t] > 0.f) ? 1.f : 0.f;
}

// ---------------- kernel: Wf2 -> Wt transposed via LDS tiles ----------------
__global__ __launch_bounds__(256) void k_wt(const float* Wf2, unsigned short* Wt) {
  __shared__ float tile[64][65];
  int tx = threadIdx.x & 63, ty = threadIdx.x >> 6;
  int k0 = blockIdx.x * 64, n0 = blockIdx.y * 64;
  for (int r = ty; r < 64; r += 4)
    tile[r][tx] = Wf2[(size_t)(k0 + r)*512 + n0 + tx];
  __syncthreads();
  for (int r = ty; r < 64; r += 4)
    Wt[(size_t)(n0 + r)*512 + k0 + tx] = f2bf(tile[tx][r]);
}

// ---------------- kernel: Wf1 -> fragment-ordered bf16 hi/lo (K padded to 32) ----------------
__global__ __launch_bounds__(256) void k_w1(const float* Wf1, unsigned short* W1h, unsigned short* W1l) {
  int id = blockIdx.x*256 + threadIdx.x;   // 16384 = 512 cols x 32 k
  int col = id & 511, k = id >> 9;
  float w = (k < 15) ? Wf1[k*512 + col] : 0.f;
  unsigned u = __float_as_uint(w);
  float hf = __uint_as_float(u & 0xffff0000u);
  float r = w - hf;
  int idx = (((col >> 4)*4 + (k >> 3))*16 + (col & 15))*8 + (k & 7);
  W1h[idx] = (unsigned short)(u >> 16);
  W1l[idx] = (unsigned short)(__float_as_uint(r) >> 16);
}

// ---------------- kernel: twiddle matrix in MFMA-fragment order, bf16 hi/lo ----------------
__global__ __launch_bounds__(256) void k_twid(unsigned short* FBh, unsigned short* FBl) {
  int col = blockIdx.x, k = threadIdx.x;
  float w = 0.f;
  if (k < 250) {
    if (col < 116) {
      int kk = (col >> 1) + 2;
      int km = (kk * k) % 500;
      float ang = (float)km * 0.012566370614359172f;  // 2pi/500
      w = (col & 1) ? sinf(ang) : cosf(ang);
    } else if (col == 116) w = (k & 1) ? -1.f : 1.f;
    else if (col == 117) w = 1.f;
  }
  unsigned u = __float_as_uint(w);
  float hf = __uint_as_float(u & 0xffff0000u);
  float r = w - hf;
  int ni2 = col >> 6, nf = (col >> 4) & 3, r15 = col & 15;
  int kt = k >> 5, lg4 = (k >> 3) & 3, e = k & 7;
  int idx = ((((kt*2 + ni2)*4 + nf)*64) + (lg4*16 + r15))*8 + e;
  FBh[idx] = (unsigned short)(u >> 16);
  FBl[idx] = (unsigned short)(__float_as_uint(r) >> 16);
}

// ---------------- kernel: chunk-DFT via MFMA (LDS-staged x) + spectral features ----------------
__global__ __launch_bounds__(256) void k_dft(const float* __restrict__ x, const float* maskf,
    const unsigned short* __restrict__ FBh, const unsigned short* __restrict__ FBl,
    float* __restrict__ bpg) {
  int c = blockIdx.x, b = blockIdx.y;
  int bc = b*64 + c;
  __shared__ __align__(16) float xs[15360];   // signal; reused as Ts[64][129]
  __shared__ float Ep[64][4];
  int t = threadIdx.x;
  float mvv = maskf[bc];
  const float4* xp4 = (const float4*)(x + (size_t)bc*15000);
  float4* xs4 = (float4*)xs;
  for (int i = t; i < 3750; i += 256) {
    float4 v = xp4[i];
    v.x *= mvv; v.y *= mvv; v.z *= mvv; v.w *= mvv;
    xs4[i] = v;
  }
  if (t < 90) xs4[3750 + t] = make_float4(0.f, 0.f, 0.f, 0.f);
  __syncthreads();
  if (t < 240) {
    int j = t >> 2, q = t & 3;
    int len = (q < 3) ? 31 : 32;
    const float2* p = (const float2*)(xs + j*250 + q*62);
    float e = 0.f;
    for (int i = 0; i < len; ++i) { float2 v = p[i]; e = fmaf(v.x, v.x, fmaf(v.y, v.y, e)); }
    Ep[j][q] = e;
  }
  int L = t & 63, wv = t >> 6;
  int mi2 = wv >> 1, ni2 = wv & 1;
  int r15 = L & 15, lg4 = L >> 4;
  f32x4 acc[2][4];
#pragma unroll
  for (int mf = 0; mf < 2; ++mf)
#pragma unroll
    for (int nf = 0; nf < 4; ++nf) acc[mf][nf] = (f32x4){0.f,0.f,0.f,0.f};
  int rowA = mi2*32 + r15;
  const unsigned short* fbh0 = FBh + (size_t)(ni2*4*64 + L)*8;
  const unsigned short* fbl0 = FBl + (size_t)(ni2*4*64 + L)*8;
  for (int kt = 0; kt < 8; ++kt) {
    int k0 = kt*32 + lg4*8;
    bf16x8 bh[4], bl[4];
#pragma unroll
    for (int nf = 0; nf < 4; ++nf) {
      bh[nf] = *(const bf16x8*)(fbh0 + (size_t)(kt*8 + nf)*512);
      bl[nf] = *(const bf16x8*)(fbl0 + (size_t)(kt*8 + nf)*512);
    }
    bf16x8 ah[2], al[2];
#pragma unroll
    for (int mf = 0; mf < 2; ++mf) {
      int row = rowA + mf*16;
      if (row > 60) row = 60;
      int base = row*250 + k0;
      float v[8];
#pragma unroll
      for (int p = 0; p < 4; ++p) {
        float2 vv = *(const float2*)(xs + base + 2*p);
        v[2*p] = vv.x; v[2*p+1] = vv.y;
      }
#pragma unroll
      for (int e = 0; e < 8; ++e) {
        unsigned u = __float_as_uint(v[e]);
        float hf = __uint_as_float(u & 0xffff0000u);
        ah[mf][e] = (short)(u >> 16);
        al[mf][e] = (short)(__float_as_uint(v[e] - hf) >> 16);
      }
    }
#pragma unroll
    for (int mf = 0; mf < 2; ++mf)
#pragma unroll
      for (int nf = 0; nf < 4; ++nf) {
        acc[mf][nf] = __builtin_amdgcn_mfma_f32_16x16x32_bf16(ah[mf], bh[nf], acc[mf][nf], 0, 0, 0);
        acc[mf][nf] = __builtin_amdgcn_mfma_f32_16x16x32_bf16(al[mf], bh[nf], acc[mf][nf], 0, 0, 0);
        acc[mf][nf] = __builtin_amdgcn_mfma_f32_16x16x32_bf16(ah[mf], bl[nf], acc[mf][nf], 0, 0, 0);
      }
  }
  __syncthreads();
  float* Ts = xs;                             // [64][129]
#pragma unroll
  for (int mf = 0; mf < 2; ++mf)
#pragma unroll
    for (int nf = 0; nf < 4; ++nf) {
      int col = ni2*64 + nf*16 + r15;
      int rw = mi2*32 + mf*16 + lg4*4;
#pragma unroll
      for (int q = 0; q < 4; ++q) Ts[(rw + q)*129 + col] = acc[mf][nf][q];
    }
  __syncthreads();
  if (t < 59) {
    int w = t;
    const float* r0 = Ts + w*129;
    const float* r1 = Ts + (w+1)*129;
    float bs0=0,bs1=0,bs2=0,bs3=0, asum=0, afsum=0, amax=0;
#pragma unroll
    for (int i = 0; i < 58; ++i) {
      float sg = (i & 1) ? -1.f : 1.f;
      float tc = fmaf(sg, r1[2*i],   r0[2*i]);
      float ts = fmaf(sg, r1[2*i+1], r0[2*i+1]);
      float P = fmaf(tc, tc, fmaf(ts, ts, EPS));
      if (i < 6) bs0 += P; else if (i < 14) bs1 += P; else if (i < 24) bs2 += P; else bs3 += P;
      if (i >= 12 && i <= 25) { asum += P; afsum = fmaf(P, 0.5f*(float)(i+2), afsum); amax = fmaxf(amax, P); }
    }
    float nyq  = r0[116] + r1[116];
    float ssum = r0[117] + r1[117];
    float en = Ep[w][0]+Ep[w][1]+Ep[w][2]+Ep[w][3] + Ep[w+1][0]+Ep[w+1][1]+Ep[w+1][2]+Ep[w+1][3];
    float E = fmaf(-ssum * (1.f/500.f), ssum, en);
    float pmean = fmaxf(fmaf(500.f, E, nyq*nyq) * (1.f/502.f) + EPS, EPS);
    float bp0 = bs0*(1.f/6.f), bp1 = bs1*(1.f/8.f), bp2 = bs2*(1.f/10.f), bp3 = bs3*(1.f/34.f);
    float afreq  = afsum / fmaxf(asum, EPS);
    float ascore = amax / pmean;
    float4* o = (float4*)(bpg + (((size_t)(b*59 + w))*64 + c)*8);
    o[0] = make_float4(bp0, bp1, bp2, bp3);
    o[1] = make_float4(afreq, ascore, 0.f, 0.f);
  }
}

// ---------------- kernel: cross-channel stats + feature/desc assembly ----------------
__global__ __launch_bounds__(64) void k_feat2(const float* __restrict__ bpg, const float* spos,
    const float* maskf, const float* regm, const float* cnts, const float* sup,
    float* feat, float* descb) {
  int w = blockIdx.x, b = blockIdx.y;
  int c = threadIdx.x, bc = b*64 + c;
  size_t bw = (size_t)(b*59 + w);
  const float4* ip = (const float4*)(bpg + (bw*64 + c)*8);
  float4 f0 = ip[0], f1 = ip[1];
  float bp0 = f0.x, bp1 = f0.y, bp2 = f0.z, bp3 = f0.w;
  float tot = fmaxf(bp0+bp1+bp2+bp3, EPS);
  float rl0 = bp0/tot, rl1 = bp1/tot, rl2 = bp2/tot, rl3 = bp3/tot;
  float valid = maskf[bc];
  float vcnt = valid;
  float ch0 = bp0*valid, ch1 = bp1*valid, ch2 = bp2*valid, ch3 = bp3*valid;
  float br0 = rl0*valid, br1 = rl1*valid, br2 = rl2*valid, br3 = rl3*valid;
  float rg0 = bp2*regm[bc], rg1 = bp2*regm[1024+bc], rg2 = bp2*regm[2048+bc], rg3 = bp2*regm[3072+bc];
#pragma unroll
  for (int off = 1; off < 64; off <<= 1) {
    vcnt += __shfl_xor(vcnt, off, 64);
    ch0 += __shfl_xor(ch0, off, 64); ch1 += __shfl_xor(ch1, off, 64);
    ch2 += __shfl_xor(ch2, off, 64); ch3 += __shfl_xor(ch3, off, 64);
    br0 += __shfl_xor(br0, off, 64); br1 += __shfl_xor(br1, off, 64);
    br2 += __shfl_xor(br2, off, 64); br3 += __shfl_xor(br3, off, 64);
    rg0 += __shfl_xor(rg0, off, 64); rg1 += __shfl_xor(rg1, off, 64);
    rg2 += __shfl_xor(rg2, off, 64); rg3 += __shfl_xor(rg3, off, 64);
  }
  float ccnt = fmaxf(vcnt, 1.f);
  float cm0 = ch0/ccnt, cm1 = ch1/ccnt, cm2 = ch2/ccnt, cm3 = ch3/ccnt;
  float lcm0 = logf(fmaxf(cm0,EPS)), lcm1 = logf(fmaxf(cm1,EPS));
  float lcm2 = logf(fmaxf(cm2,EPS)), lcm3 = logf(fmaxf(cm3,EPS));
  float lg0 = logf(fmaxf(bp0,EPS)), lg1 = logf(fmaxf(bp1,EPS));
  float lg2 = logf(fmaxf(bp2,EPS)), lg3 = logf(fmaxf(bp3,EPS));
  float* fr = feat + (bw*64 + c)*16;
  fr[0]=lg0; fr[1]=lg1; fr[2]=lg2; fr[3]=lg3;
  fr[4]=rl0; fr[5]=rl1; fr[6]=rl2; fr[7]=rl3;
  fr[8]=lg0-lcm0; fr[9]=lg1-lcm1; fr[10]=lg2-lcm2; fr[11]=lg3-lcm3;
  fr[12]=f1.x;
  fr[13]=f1.y;
  fr[14]=spos[bc*2 + 1];
  fr[15]=0.f;                                  // K-pad slot must be clean
  if (c == 0) {
    float bR0 = br0/ccnt, bR1 = br1/ccnt, bR2 = br2/ccnt, bR3 = br3/ccnt;
    float Lm = rg0 / fmaxf(cnts[b],      1.f);
    float Rm = rg1 / fmaxf(cnts[16+b],   1.f);
    float Pm = rg2 / fmaxf(cnts[32+b],   1.f);
    float Am = rg3 / fmaxf(cnts[48+b],   1.f);
    float* dr = descb + bw*16;
    dr[0]=lcm0; dr[1]=lcm1; dr[2]=lcm2; dr[3]=lcm3;
    dr[4]=bR0; dr[5]=bR1; dr[6]=bR2; dr[7]=bR3;
    dr[8]=(Lm - Rm) / fmaxf(Lm + Rm + EPS, EPS);
    dr[9]=(sup[b] > 0.5f) ? (Pm - Am) / fmaxf(Pm + Am + EPS, EPS) : 0.f;
    dr[10]=bR0 + bR1;
  }
}

// ---------------- kernel: fused MLP1(MFMA)+GELU + GEMM2 + bias + LayerNorm -> tokens ----------------
// 512 threads = 8 waves. Per kt: waves 4-7 stage Bs (8 gload16 each) while waves 0-3 JIT-compute
// the 64x32 h-slice (6 MFMA + GELU) and write swizzled As. GEMM: wave (wm=wv>>2, wn=wv&3) owns
// 32 rows x 128 cols -> acc[2][8] (64 acc VGPRs -> 4 waves/SIMD occupancy).
__global__ __launch_bounds__(512, 4) void k_tok(const float* __restrict__ feat,
    const unsigned short* __restrict__ W1h, const unsigned short* __restrict__ W1l,
    const float* __restrict__ bf1, const unsigned short* __restrict__ Wt,
    const float* bf2, const float* lng, const float* lnb, float* out) {
  __shared__ __align__(16) unsigned short As[64*32];
  __shared__ __align__(16) unsigned short Bs[512*32];
  __shared__ float b1s[512];
  __shared__ float red[64][4][2];
  __shared__ float lnp[64][2];
  int t = threadIdx.x;
  int L = t & 63, wv = t >> 6;
  int wm = wv >> 2, wn = wv & 3;
  int row0 = blockIdx.x * 64;
  int r15 = L & 15, lg4 = L >> 4;
  if (t < 512) b1s[t] = bf1[t];
  // A1 fragment for JIT waves (wv<4): rows wv*16..+16 of feat, K=16 in k-lanes lg4<2
  bf16x8 a1h = (bf16x8){0,0,0,0,0,0,0,0}, a1l = (bf16x8){0,0,0,0,0,0,0,0};
  if (wv < 4 && lg4 < 2) {
    int row = row0 + wv*16 + r15;
    const float4* fp = (const float4*)(feat + (size_t)row*16 + lg4*8);
    float4 v0 = fp[0], v1 = fp[1];
    float v[8] = {v0.x, v0.y, v0.z, v0.w, v1.x, v1.y, v1.z, v1.w};
#pragma unroll
    for (int e = 0; e < 8; ++e) {
      unsigned u = __float_as_uint(v[e]);
      float hf = __uint_as_float(u & 0xffff0000u);
      a1h[e] = (short)(u >> 16);
      a1l[e] = (short)(__float_as_uint(v[e] - hf) >> 16);
    }
  }
  f32x4 acc[2][8];
#pragma unroll
  for (int m = 0; m < 2; ++m)
#pragma unroll
    for (int n = 0; n < 8; ++n) acc[m][n] = (f32x4){0.f,0.f,0.f,0.f};
  int swz = (r15 >> 1) & 3;
  int kca = lg4 ^ swz;
  __syncthreads();                                         // b1s ready
  for (int kt = 0; kt < 16; ++kt) {
    if (wv >= 4) {
      // staging waves: 256 threads x 8 gload16 = 2048 x 16B = full Bs k-slice
      int ts = t - 256;
#pragma unroll
      for (int r = 0; r < 8; ++r) {
        int n = r*256 + ts;
        int col = n >> 2;
        int kc = (n & 3) ^ ((n >> 3) & 3);
        gload16(Wt + (size_t)col*512 + kt*32 + kc*8, (char*)Bs + n*16);
      }
    } else {
      // JIT waves: h-slice = feat @ Wf1[:, kt*32..+32] (hi/lo MFMA) + bias + GELU
      f32x4 acc1[2];
      acc1[0] = (f32x4){0.f,0.f,0.f,0.f};
      acc1[1] = (f32x4){0.f,0.f,0.f,0.f};
#pragma unroll
      for (int n2 = 0; n2 < 2; ++n2) {
        bf16x8 b1h = *(const bf16x8*)(W1h + (size_t)(kt*2 + n2)*512 + L*8);
        bf16x8 b1l = *(const bf16x8*)(W1l + (size_t)(kt*2 + n2)*512 + L*8);
        acc1[n2] = __builtin_amdgcn_mfma_f32_16x16x32_bf16(a1h, b1h, acc1[n2], 0, 0, 0);
        acc1[n2] = __builtin_amdgcn_mfma_f32_16x16x32_bf16(a1l, b1h, acc1[n2], 0, 0, 0);
        acc1[n2] = __builtin_amdgcn_mfma_f32_16x16x32_bf16(a1h, b1l, acc1[n2], 0, 0, 0);
      }
      unsigned short hv[8];
#pragma unroll
      for (int n2 = 0; n2 < 2; ++n2) {
        float bb = b1s[kt*32 + n2*16 + r15];
#pragma unroll
        for (int q = 0; q < 4; ++q)
          hv[n2*4 + q] = f2bf(gelu_f(acc1[n2][q] + bb));
      }
#pragma unroll
      for (int n2 = 0; n2 < 2; ++n2) {
        int col5 = n2*16 + r15;                  // 0..31 within slice
        int cb = col5 >> 3;
#pragma unroll
        for (int q = 0; q < 4; ++q) {
          int rw = wv*16 + lg4*4 + q;
          int kcs = cb ^ ((rw >> 1) & 3);
          As[rw*32 + kcs*8 + (col5 & 7)] = hv[n2*4 + q];
        }
      }
    }
    __syncthreads();                           // As visible + Bs resident
    bf16x8 av[2], bv[8];
#pragma unroll
    for (int m = 0; m < 2; ++m)
      av[m] = *(const bf16x8*)&As[(wm*32 + m*16 + r15)*32 + kca*8];
#pragma unroll
    for (int n = 0; n < 8; ++n)
      bv[n] = *(const bf16x8*)&Bs[(wn*128 + n*16 + r15)*32 + kca*8];
#pragma unroll
    for (int m = 0; m < 2; ++m)
#pragma unroll
      for (int n = 0; n < 8; ++n)
        acc[m][n] = __builtin_amdgcn_mfma_f32_16x16x32_bf16(av[m], bv[n], acc[m][n], 0, 0, 0);
    __syncthreads();                           // all reads done before next stage/write
  }
  // epilogue: bias + per-row mean/var over 512 cols + LN
  float b2v[8], gv[8], btv[8];
#pragma unroll
  for (int n = 0; n < 8; ++n) {
    int col = wn*128 + n*16 + r15;
    b2v[n] = bf2[col]; gv[n] = lng[col]; btv[n] = lnb[col];
  }
  float s1[2][4], s2[2][4];
#pragma unroll
  for (int m = 0; m < 2; ++m)
#pragma unroll
    for (int r = 0; r < 4; ++r) { s1[m][r] = 0.f; s2[m][r] = 0.f; }
#pragma unroll
  for (int m = 0; m < 2; ++m)
#pragma unroll
    for (int n = 0; n < 8; ++n)
#pragma unroll
      for (int r = 0; r < 4; ++r) {
        float z = acc[m][n][r] + b2v[n];
        acc[m][n][r] = z;
        s1[m][r] += z;
        s2[m][r] = fmaf(z, z, s2[m][r]);
      }
#pragma unroll
  for (int off = 1; off < 16; off <<= 1)
#pragma unroll
    for (int m = 0; m < 2; ++m)
#pragma unroll
      for (int r = 0; r < 4; ++r) {
        s1[m][r] += __shfl_xor(s1[m][r], off, 64);
        s2[m][r] += __shfl_xor(s2[m][r], off, 64);
      }
  if (r15 == 0) {
#pragma unroll
    for (int m = 0; m < 2; ++m)
#pragma unroll
      for (int r = 0; r < 4; ++r) {
        int rw = wm*32 + m*16 + lg4*4 + r;
        red[rw][wn][0] = s1[m][r];
        red[rw][wn][1] = s2[m][r];
      }
  }
  __syncthreads();
  if (t < 64) {
    float a = red[t][0][0] + red[t][1][0] + red[t][2][0] + red[t][3][0];
    float q = red[t][0][1] + red[t][1][1] + red[t][2][1] + red[t][3][1];
    float mu = a * (1.f/512.f);
    float var = q * (1.f/512.f) - mu*mu;
    lnp[t][0] = mu;
    lnp[t][1] = rsqrtf(var + LN_EPS);
  }
  __syncthreads();
  float* ob = out + (size_t)row0*512;
#pragma unroll
  for (int m = 0; m < 2; ++m)
#pragma unroll
    for (int r = 0; r < 4; ++r) {
      int rw = wm*32 + m*16 + lg4*4 + r;
      float mu = lnp[rw][0], rs = lnp[rw][1];
#pragma unroll
      for (int n = 0; n < 8; ++n) {
        int col = wn*128 + n*16 + r15;
        ob[(size_t)rw*512 + col] = fmaf((acc[m][n][r] - mu)*rs, gv[n], btv[n]);
      }
    }
}

// ---------------- kernel: desc MLP (f32) -> desc_out ----------------
__global__ __launch_bounds__(256) void k_desc(const float* descb, const float* Wd1, const float* bd1,
    const float* Wd2, const float* bd2, float* out) {
  int blk = blockIdx.x;
  int cq = blockIdx.y;
  __shared__ float ds[16][12];
  __shared__ float hd[16*512];
  int t = threadIdx.x;
  { int r = t >> 4, cc = t & 15;
    if (cc < 11) ds[r][cc] = descb[(size_t)(blk*16 + r)*16 + cc]; }
  __syncthreads();
  {
    int c0 = t, c1 = t + 256;
    float wa[11], wb[11];
#pragma unroll
    for (int k = 0; k < 11; ++k) { wa[k] = Wd1[k*512+c0]; wb[k] = Wd1[k*512+c1]; }
    float ba = bd1[c0], bb = bd1[c1];
    for (int r = 0; r < 16; ++r) {
      float a0 = ba, a1 = bb;
#pragma unroll
      for (int k = 0; k < 11; ++k) { float f = ds[r][k]; a0 = fmaf(f, wa[k], a0); a1 = fmaf(f, wb[k], a1); }
      hd[r*512+c0] = gelu_f(a0);
      hd[r*512+c1] = gelu_f(a1);
    }
  }
  __syncthreads();
  int col = cq*128 + (t & 127);
  int half = t >> 7;
  float accv[8];
  float bz = bd2[col];
#pragma unroll
  for (int r = 0; r < 8; ++r) accv[r] = bz;
  for (int k4 = 0; k4 < 128; ++k4) {
    float w0 = Wd2[(size_t)(k4*4+0)*512 + col];
    float w1 = Wd2[(size_t)(k4*4+1)*512 + col];
    float w2 = Wd2[(size_t)(k4*4+2)*512 + col];
    float w3 = Wd2[(size_t)(k4*4+3)*512 + col];
#pragma unroll
    for (int r = 0; r < 8; ++r) {
      float4 hv = *(const float4*)&hd[(half*8+r)*512 + k4*4];
      accv[r] = fmaf(hv.x, w0, fmaf(hv.y, w1, fmaf(hv.z, w2, fmaf(hv.w, w3, accv[r]))));
    }
  }
  float* ob = out + TOKENS_N;
#pragma unroll
  for (int r = 0; r < 8; ++r) {
    int grow = blk*16 + half*8 + r;
    ob[(size_t)grow*512 + col] = accv[r];
  }
}

// ---------------- launch ----------------
extern "C" void kernel_launch(void* const* d_in, const int* in_sizes, int n_in,
                              void* d_out, int out_size, void* d_ws, size_t ws_size,
                              hipStream_t stream) {
  (void)in_sizes; (void)n_in; (void)out_size; (void)ws_size;
  const float* x    = (const float*)d_in[0];
  const float* spos = (const float*)d_in[1];
  const void*  mask = d_in[2];
  const float* Wf1  = (const float*)d_in[3];
  const float* bf1  = (const float*)d_in[4];
  const float* Wf2  = (const float*)d_in[5];
  const float* bf2  = (const float*)d_in[6];
  const float* lng  = (const float*)d_in[7];
  const float* lnb  = (const float*)d_in[8];
  const float* Wd1  = (const float*)d_in[9];
  const float* bd1  = (const float*)d_in[10];
  const float* Wd2  = (const float*)d_in[11];
  const float* bd2  = (const float*)d_in[12];
  char* ws = (char*)d_ws;
  float*          bpg   = (float*)(ws + BP_OFF);
  unsigned short* FBh   = (unsigned short*)(ws + BTH_OFF);
  unsigned short* FBl   = (unsigned short*)(ws + BTL_OFF);
  float*          feat  = (float*)(ws + FEAT_OFF);
  unsigned short* W1h   = (unsigned short*)(ws + W1H_OFF);
  unsigned short* W1l   = (unsigned short*)(ws + W1L_OFF);
  unsigned short* Wt    = (unsigned short*)(ws + WT_OFF);
  float*          descb = (float*)(ws + DSC_OFF);
  float*          maskf = (float*)(ws + MSK_OFF);
  float*          regm  = (float*)(ws + REG_OFF);
  float*          cnts  = (float*)(ws + CNT_OFF);
  float*          sup   = (float*)(ws + SUP_OFF);
  float*          out   = (float*)d_out;

  hipLaunchKernelGGL(k_setup,  dim3(1),      dim3(1024), 0, stream, mask, spos, maskf, regm, cnts, sup);
  hipLaunchKernelGGL(k_wt,     dim3(8,8),    dim3(256),  0, stream, Wf2, Wt);
  hipLaunchKernelGGL(k_w1,     dim3(64),     dim3(256),  0, stream, Wf1, W1h, W1l);
  hipLaunchKernelGGL(k_twid,   dim3(128),    dim3(256),  0, stream, FBh, FBl);
  hipLaunchKernelGGL(k_dft,    dim3(64,16),  dim3(256),  0, stream, x, maskf, FBh, FBl, bpg);
  hipLaunchKernelGGL(k_feat2,  dim3(59,16),  dim3(64),   0, stream, bpg, spos, maskf, regm, cnts, sup, feat, descb);
  hipLaunchKernelGGL(k_tok,    dim3(944),    dim3(512),  0, stream, feat, W1h, W1l, bf1, Wt, bf2, lng, lnb, out);
  hipLaunchKernelGGL(k_desc,   dim3(59,4),   dim3(256),  0, stream, descb, Wd1, bd1, Wd2, bd2, out);
}

// Round 7
// 339.060 us; speedup vs baseline: 1.1222x; 1.1222x over previous
//
#include <hip/hip_runtime.h>
#include <math.h>

#define EPS 1e-6f
#define LN_EPS 1e-5f

typedef __attribute__((ext_vector_type(8))) short bf16x8;
typedef __attribute__((ext_vector_type(4))) float f32x4;

// ---------------- workspace layout (bytes) ----------------
#define SD_OFF    0ULL
#define SD_SZ     (1024ULL*60*128*4)
#define BP_OFF    SD_OFF                    // [B*W*C][8] band powers + alpha feats
#define BTH_OFF   (SD_OFF + 4ULL*1024*1024) // FBh fragment-ordered twiddles (64KB)
#define BTL_OFF   (BTH_OFF + 65536ULL)      // FBl (64KB)
#define FEAT_OFF  (SD_OFF + SD_SZ)
#define FEAT_SZ   (60416ULL*16*4)
#define W1H_OFF   (FEAT_OFF + FEAT_SZ)      // Wf1 fragment-ordered hi (32KB)
#define W1L_OFF   (W1H_OFF + 32768ULL)      // lo (32KB)
#define WT_OFF    (W1L_OFF + 32768ULL)
#define WT_SZ     (512ULL*512*2)
#define DSC_OFF   (WT_OFF + WT_SZ)
#define DSC_SZ    (944ULL*16*4)
#define MSK_OFF   (DSC_OFF + DSC_SZ)
#define MSK_SZ    (1024ULL*4)
#define REG_OFF   (MSK_OFF + MSK_SZ)
#define REG_SZ    (4096ULL*4)
#define CNT_OFF   (REG_OFF + REG_SZ)
#define CNT_SZ    (64ULL*4)
#define SUP_OFF   (CNT_OFF + CNT_SZ)

#define TOKENS_N  30932992ULL               // 16*59*64*512

__device__ inline unsigned short f2bf(float f) {
  union { float f; unsigned u; } v; v.f = f;
  unsigned u = v.u;
  return (unsigned short)((u + 0x7fffu + ((u >> 16) & 1u)) >> 16);  // RNE
}

__device__ inline void gload16(const void* g, void* l) {
  __builtin_amdgcn_global_load_lds((const __attribute__((address_space(1))) unsigned int*)g,
                                   (__attribute__((address_space(3))) unsigned int*)l, 16, 0, 0);
}

// exact-GELU via Abramowitz-Stegun 7.1.26 erf (|err|<1.5e-7 << bf16 eps)
__device__ inline float gelu_f(float z) {
  float s = z * 0.70710678118654752f;
  float a = fabsf(s);
  float t = __builtin_amdgcn_rcpf(fmaf(0.3275911f, a, 1.f));
  float p = t*(0.254829592f + t*(-0.284496736f + t*(1.421413741f + t*(-1.453152027f + t*1.061405429f))));
  float e = __expf(-a*a);
  float er = copysignf(fmaf(-p, e, 1.f), s);
  return 0.5f * z * (1.f + er);
}

// ---------------- kernel: setup ----------------
__global__ __launch_bounds__(1024) void k_setup(const void* mraw, const float* spos,
    float* maskf, float* regm, float* cnts, float* sup) {
  __shared__ int okint, okflt;
  __shared__ int anyr[4];
  __shared__ float cbuf[4][16];
  int t = threadIdx.x;
  if (t == 0) { okint = 1; okflt = 1; }
  if (t < 4) anyr[t] = 0;
  if (t < 64) cbuf[t>>4][t&15] = 0.f;
  __syncthreads();
  if (t < 256) {
    unsigned v = ((const unsigned*)mraw)[t];
    if (v > 1u) okint = 0;
    if (v != 0u && v != 0x3f800000u) okflt = 0;
  }
  __syncthreads();
  float mv;
  if (okint)      mv = (float)((const int*)mraw)[t];
  else if (okflt) mv = ((const float*)mraw)[t];
  else            mv = (float)((const unsigned char*)mraw)[t];
  maskf[t] = mv;
  bool mk = mv > 0.5f;
  float px = spos[2*t], py = spos[2*t+1];
  int lm = ((px < -0.02f) && mk) ? 1 : 0;
  int rm = ((px >  0.02f) && mk) ? 1 : 0;
  int pm = ((py < -0.02f) && mk) ? 1 : 0;
  int am = ((py >  0.02f) && mk) ? 1 : 0;
  if (lm) anyr[0] = 1;
  if (rm) anyr[1] = 1;
  if (pm) anyr[2] = 1;
  if (am) anyr[3] = 1;
  __syncthreads();
  float lv = anyr[0] ? (float)lm : 0.f;
  float rv = anyr[1] ? (float)rm : 0.f;
  float pv = anyr[2] ? (float)pm : 1.f;   // posterior fallback = True
  float av = anyr[3] ? (float)am : 0.f;
  regm[t] = lv; regm[1024+t] = rv; regm[2048+t] = pv; regm[3072+t] = av;
  int b = t >> 6;
  atomicAdd(&cbuf[0][b], lv);
  atomicAdd(&cbuf[1][b], rv);
  atomicAdd(&cbuf[2][b], pv);
  atomicAdd(&cbuf[3][b], av);
  __syncthreads();
  if (t < 64) cnts[t] = cbuf[t>>4][t&15];
  if (t < 16) sup[t] = (cbuf[3][t] > 0.f && cbuf[2][t] > 0.f) ? 1.f : 0.f;
}

// ---------------- kernel: Wf2 -> Wt transposed via LDS tiles ----------------
__global__ __launch_bounds__(256) void k_wt(const float* Wf2, unsigned short* Wt) {
  __shared__ float tile[64][65];
  int tx = threadIdx.x & 63, ty = threadIdx.x >> 6;
  int k0 = blockIdx.x * 64, n0 = blockIdx.y * 64;
  for (int r = ty; r < 64; r += 4)
    tile[r][tx] = Wf2[(size_t)(k0 + r)*512 + n0 + tx];
  __syncthreads();
  for (int r = ty; r < 64; r += 4)
    Wt[(size_t)(n0 + r)*512 + k0 + tx] = f2bf(tile[tx][r]);
}

// ---------------- kernel: Wf1 -> fragment-ordered bf16 hi/lo (K padded to 32) ----------------
__global__ __launch_bounds__(256) void k_w1(const float* Wf1, unsigned short* W1h, unsigned short* W1l) {
  int id = blockIdx.x*256 + threadIdx.x;   // 16384 = 512 cols x 32 k
  int col = id & 511, k = id >> 9;
  float w = (k < 15) ? Wf1[k*512 + col] : 0.f;
  unsigned u = __float_as_uint(w);
  float hf = __uint_as_float(u & 0xffff0000u);
  float r = w - hf;
  int idx = (((col >> 4)*4 + (k >> 3))*16 + (col & 15))*8 + (k & 7);
  W1h[idx] = (unsigned short)(u >> 16);
  W1l[idx] = (unsigned short)(__float_as_uint(r) >> 16);
}

// ---------------- kernel: twiddle matrix in MFMA-fragment order, bf16 hi/lo ----------------
__global__ __launch_bounds__(256) void k_twid(unsigned short* FBh, unsigned short* FBl) {
  int col = blockIdx.x, k = threadIdx.x;
  float w = 0.f;
  if (k < 250) {
    if (col < 116) {
      int kk = (col >> 1) + 2;
      int km = (kk * k) % 500;
      float ang = (float)km * 0.012566370614359172f;  // 2pi/500
      w = (col & 1) ? sinf(ang) : cosf(ang);
    } else if (col == 116) w = (k & 1) ? -1.f : 1.f;
    else if (col == 117) w = 1.f;
  }
  unsigned u = __float_as_uint(w);
  float hf = __uint_as_float(u & 0xffff0000u);
  float r = w - hf;
  int ni2 = col >> 6, nf = (col >> 4) & 3, r15 = col & 15;
  int kt = k >> 5, lg4 = (k >> 3) & 3, e = k & 7;
  int idx = ((((kt*2 + ni2)*4 + nf)*64) + (lg4*16 + r15))*8 + e;
  FBh[idx] = (unsigned short)(u >> 16);
  FBl[idx] = (unsigned short)(__float_as_uint(r) >> 16);
}

// ---------------- kernel: chunk-DFT via MFMA (LDS-staged x) + spectral features ----------------
__global__ __launch_bounds__(256) void k_dft(const float* __restrict__ x, const float* maskf,
    const unsigned short* __restrict__ FBh, const unsigned short* __restrict__ FBl,
    float* __restrict__ bpg) {
  int c = blockIdx.x, b = blockIdx.y;
  int bc = b*64 + c;
  __shared__ __align__(16) float xs[15360];   // signal; reused as Ts[64][129]
  __shared__ float Ep[64][4];
  int t = threadIdx.x;
  float mvv = maskf[bc];
  const float4* xp4 = (const float4*)(x + (size_t)bc*15000);
  float4* xs4 = (float4*)xs;
  for (int i = t; i < 3750; i += 256) {
    float4 v = xp4[i];
    v.x *= mvv; v.y *= mvv; v.z *= mvv; v.w *= mvv;
    xs4[i] = v;
  }
  if (t < 90) xs4[3750 + t] = make_float4(0.f, 0.f, 0.f, 0.f);
  __syncthreads();
  if (t < 240) {
    int j = t >> 2, q = t & 3;
    int len = (q < 3) ? 31 : 32;
    const float2* p = (const float2*)(xs + j*250 + q*62);
    float e = 0.f;
    for (int i = 0; i < len; ++i) { float2 v = p[i]; e = fmaf(v.x, v.x, fmaf(v.y, v.y, e)); }
    Ep[j][q] = e;
  }
  int L = t & 63, wv = t >> 6;
  int mi2 = wv >> 1, ni2 = wv & 1;
  int r15 = L & 15, lg4 = L >> 4;
  f32x4 acc[2][4];
#pragma unroll
  for (int mf = 0; mf < 2; ++mf)
#pragma unroll
    for (int nf = 0; nf < 4; ++nf) acc[mf][nf] = (f32x4){0.f,0.f,0.f,0.f};
  int rowA = mi2*32 + r15;
  const unsigned short* fbh0 = FBh + (size_t)(ni2*4*64 + L)*8;
  const unsigned short* fbl0 = FBl + (size_t)(ni2*4*64 + L)*8;
  for (int kt = 0; kt < 8; ++kt) {
    int k0 = kt*32 + lg4*8;
    bf16x8 bh[4], bl[4];
#pragma unroll
    for (int nf = 0; nf < 4; ++nf) {
      bh[nf] = *(const bf16x8*)(fbh0 + (size_t)(kt*8 + nf)*512);
      bl[nf] = *(const bf16x8*)(fbl0 + (size_t)(kt*8 + nf)*512);
    }
    bf16x8 ah[2], al[2];
#pragma unroll
    for (int mf = 0; mf < 2; ++mf) {
      int row = rowA + mf*16;
      if (row > 60) row = 60;
      int base = row*250 + k0;
      float v[8];
#pragma unroll
      for (int p = 0; p < 4; ++p) {
        float2 vv = *(const float2*)(xs + base + 2*p);
        v[2*p] = vv.x; v[2*p+1] = vv.y;
      }
#pragma unroll
      for (int e = 0; e < 8; ++e) {
        unsigned u = __float_as_uint(v[e]);
        float hf = __uint_as_float(u & 0xffff0000u);
        ah[mf][e] = (short)(u >> 16);
        al[mf][e] = (short)(__float_as_uint(v[e] - hf) >> 16);
      }
    }
#pragma unroll
    for (int mf = 0; mf < 2; ++mf)
#pragma unroll
      for (int nf = 0; nf < 4; ++nf) {
        acc[mf][nf] = __builtin_amdgcn_mfma_f32_16x16x32_bf16(ah[mf], bh[nf], acc[mf][nf], 0, 0, 0);
        acc[mf][nf] = __builtin_amdgcn_mfma_f32_16x16x32_bf16(al[mf], bh[nf], acc[mf][nf], 0, 0, 0);
        acc[mf][nf] = __builtin_amdgcn_mfma_f32_16x16x32_bf16(ah[mf], bl[nf], acc[mf][nf], 0, 0, 0);
      }
  }
  __syncthreads();
  float* Ts = xs;                             // [64][129]
#pragma unroll
  for (int mf = 0; mf < 2; ++mf)
#pragma unroll
    for (int nf = 0; nf < 4; ++nf) {
      int col = ni2*64 + nf*16 + r15;
      int rw = mi2*32 + mf*16 + lg4*4;
#pragma unroll
      for (int q = 0; q < 4; ++q) Ts[(rw + q)*129 + col] = acc[mf][nf][q];
    }
  __syncthreads();
  if (t < 59) {
    int w = t;
    const float* r0 = Ts + w*129;
    const float* r1 = Ts + (w+1)*129;
    float bs0=0,bs1=0,bs2=0,bs3=0, asum=0, afsum=0, amax=0;
#pragma unroll
    for (int i = 0; i < 58; ++i) {
      float sg = (i & 1) ? -1.f : 1.f;
      float tc = fmaf(sg, r1[2*i],   r0[2*i]);
      float ts = fmaf(sg, r1[2*i+1], r0[2*i+1]);
      float P = fmaf(tc, tc, fmaf(ts, ts, EPS));
      if (i < 6) bs0 += P; else if (i < 14) bs1 += P; else if (i < 24) bs2 += P; else bs3 += P;
      if (i >= 12 && i <= 25) { asum += P; afsum = fmaf(P, 0.5f*(float)(i+2), afsum); amax = fmaxf(amax, P); }
    }
    float nyq  = r0[116] + r1[116];
    float ssum = r0[117] + r1[117];
    float en = Ep[w][0]+Ep[w][1]+Ep[w][2]+Ep[w][3] + Ep[w+1][0]+Ep[w+1][1]+Ep[w+1][2]+Ep[w+1][3];
    float E = fmaf(-ssum * (1.f/500.f), ssum, en);
    float pmean = fmaxf(fmaf(500.f, E, nyq*nyq) * (1.f/502.f) + EPS, EPS);
    float bp0 = bs0*(1.f/6.f), bp1 = bs1*(1.f/8.f), bp2 = bs2*(1.f/10.f), bp3 = bs3*(1.f/34.f);
    float afreq  = afsum / fmaxf(asum, EPS);
    float ascore = amax / pmean;
    float4* o = (float4*)(bpg + (((size_t)(b*59 + w))*64 + c)*8);
    o[0] = make_float4(bp0, bp1, bp2, bp3);
    o[1] = make_float4(afreq, ascore, 0.f, 0.f);
  }
}

// ---------------- kernel: cross-channel stats + feature/desc assembly ----------------
__global__ __launch_bounds__(64) void k_feat2(const float* __restrict__ bpg, const float* spos,
    const float* maskf, const float* regm, const float* cnts, const float* sup,
    float* feat, float* descb) {
  int w = blockIdx.x, b = blockIdx.y;
  int c = threadIdx.x, bc = b*64 + c;
  size_t bw = (size_t)(b*59 + w);
  const float4* ip = (const float4*)(bpg + (bw*64 + c)*8);
  float4 f0 = ip[0], f1 = ip[1];
  float bp0 = f0.x, bp1 = f0.y, bp2 = f0.z, bp3 = f0.w;
  float tot = fmaxf(bp0+bp1+bp2+bp3, EPS);
  float rl0 = bp0/tot, rl1 = bp1/tot, rl2 = bp2/tot, rl3 = bp3/tot;
  float valid = maskf[bc];
  float vcnt = valid;
  float ch0 = bp0*valid, ch1 = bp1*valid, ch2 = bp2*valid, ch3 = bp3*valid;
  float br0 = rl0*valid, br1 = rl1*valid, br2 = rl2*valid, br3 = rl3*valid;
  float rg0 = bp2*regm[bc], rg1 = bp2*regm[1024+bc], rg2 = bp2*regm[2048+bc], rg3 = bp2*regm[3072+bc];
#pragma unroll
  for (int off = 1; off < 64; off <<= 1) {
    vcnt += __shfl_xor(vcnt, off, 64);
    ch0 += __shfl_xor(ch0, off, 64); ch1 += __shfl_xor(ch1, off, 64);
    ch2 += __shfl_xor(ch2, off, 64); ch3 += __shfl_xor(ch3, off, 64);
    br0 += __shfl_xor(br0, off, 64); br1 += __shfl_xor(br1, off, 64);
    br2 += __shfl_xor(br2, off, 64); br3 += __shfl_xor(br3, off, 64);
    rg0 += __shfl_xor(rg0, off, 64); rg1 += __shfl_xor(rg1, off, 64);
    rg2 += __shfl_xor(rg2, off, 64); rg3 += __shfl_xor(rg3, off, 64);
  }
  float ccnt = fmaxf(vcnt, 1.f);
  float cm0 = ch0/ccnt, cm1 = ch1/ccnt, cm2 = ch2/ccnt, cm3 = ch3/ccnt;
  float lcm0 = logf(fmaxf(cm0,EPS)), lcm1 = logf(fmaxf(cm1,EPS));
  float lcm2 = logf(fmaxf(cm2,EPS)), lcm3 = logf(fmaxf(cm3,EPS));
  float lg0 = logf(fmaxf(bp0,EPS)), lg1 = logf(fmaxf(bp1,EPS));
  float lg2 = logf(fmaxf(bp2,EPS)), lg3 = logf(fmaxf(bp3,EPS));
  float* fr = feat + (bw*64 + c)*16;
  fr[0]=lg0; fr[1]=lg1; fr[2]=lg2; fr[3]=lg3;
  fr[4]=rl0; fr[5]=rl1; fr[6]=rl2; fr[7]=rl3;
  fr[8]=lg0-lcm0; fr[9]=lg1-lcm1; fr[10]=lg2-lcm2; fr[11]=lg3-lcm3;
  fr[12]=f1.x;
  fr[13]=f1.y;
  fr[14]=spos[bc*2 + 1];
  fr[15]=0.f;                                  // K-pad slot must be clean
  if (c == 0) {
    float bR0 = br0/ccnt, bR1 = br1/ccnt, bR2 = br2/ccnt, bR3 = br3/ccnt;
    float Lm = rg0 / fmaxf(cnts[b],      1.f);
    float Rm = rg1 / fmaxf(cnts[16+b],   1.f);
    float Pm = rg2 / fmaxf(cnts[32+b],   1.f);
    float Am = rg3 / fmaxf(cnts[48+b],   1.f);
    float* dr = descb + bw*16;
    dr[0]=lcm0; dr[1]=lcm1; dr[2]=lcm2; dr[3]=lcm3;
    dr[4]=bR0; dr[5]=bR1; dr[6]=bR2; dr[7]=bR3;
    dr[8]=(Lm - Rm) / fmaxf(Lm + Rm + EPS, EPS);
    dr[9]=(sup[b] > 0.5f) ? (Pm - Am) / fmaxf(Pm + Am + EPS, EPS) : 0.f;
    dr[10]=bR0 + bR1;
  }
}

// ---------------- kernel: fused MLP1(MFMA)+GELU + GEMM2 + bias + LayerNorm -> tokens ----------------
// 256 threads / 4 waves (R4 geometry, no spill). Double-buffered As/Bs: per kt, stage Bs[nxt]
// (gload16) + JIT h(kt+1)->As[nxt], then GEMM on [cur], then ONE barrier. Loads drain under compute.
__global__ __launch_bounds__(256, 2) void k_tok(const float* __restrict__ feat,
    const unsigned short* __restrict__ W1h, const unsigned short* __restrict__ W1l,
    const float* __restrict__ bf1, const unsigned short* __restrict__ Wt,
    const float* bf2, const float* lng, const float* lnb, float* out) {
  __shared__ __align__(16) unsigned short As[2][64*32];
  __shared__ __align__(16) unsigned short Bs[2][512*32];
  __shared__ float b1s[512];
  __shared__ float red[64][4][2];
  __shared__ float lnp[64][2];
  int t = threadIdx.x;
  int L = t & 63, wvid = t >> 6;
  int row0 = blockIdx.x * 64;
  int r15 = L & 15, lg4 = L >> 4;
  { b1s[t] = bf1[t]; b1s[256+t] = bf1[256+t]; }
  // A1 fragment (loop-invariant): rows wvid*16..+16 of feat, K=16 in k-lanes lg4<2
  bf16x8 a1h = (bf16x8){0,0,0,0,0,0,0,0}, a1l = (bf16x8){0,0,0,0,0,0,0,0};
  if (lg4 < 2) {
    int row = row0 + wvid*16 + r15;
    const float4* fp = (const float4*)(feat + (size_t)row*16 + lg4*8);
    float4 v0 = fp[0], v1 = fp[1];
    float v[8] = {v0.x, v0.y, v0.z, v0.w, v1.x, v1.y, v1.z, v1.w};
#pragma unroll
    for (int e = 0; e < 8; ++e) {
      unsigned u = __float_as_uint(v[e]);
      float hf = __uint_as_float(u & 0xffff0000u);
      a1h[e] = (short)(u >> 16);
      a1l[e] = (short)(__float_as_uint(v[e] - hf) >> 16);
    }
  }
  f32x4 acc[4][8];
#pragma unroll
  for (int m = 0; m < 4; ++m)
#pragma unroll
    for (int n = 0; n < 8; ++n) acc[m][n] = (f32x4){0.f,0.f,0.f,0.f};
  int swz = (r15 >> 1) & 3;
  int kca = lg4 ^ swz;
  int aoff = r15*32 + kca*8;                               // shorts
  int boff = (wvid*128 + r15)*32 + kca*8;                  // shorts

#define STAGE_BS(KT, BUF) do { \
    _Pragma("unroll") \
    for (int r_ = 0; r_ < 8; ++r_) { \
      int n_ = r_*256 + t; \
      int col_ = n_ >> 2; \
      int kc_ = (n_ & 3) ^ ((n_ >> 3) & 3); \
      gload16(Wt + (size_t)col_*512 + (KT)*32 + kc_*8, (char*)&Bs[BUF][0] + n_*16); \
    } } while (0)

#define JIT_H(KT, BUF) do { \
    f32x4 acc1_[2]; \
    acc1_[0] = (f32x4){0.f,0.f,0.f,0.f}; \
    acc1_[1] = (f32x4){0.f,0.f,0.f,0.f}; \
    _Pragma("unroll") \
    for (int n2_ = 0; n2_ < 2; ++n2_) { \
      bf16x8 b1h_ = *(const bf16x8*)(W1h + (size_t)((KT)*2 + n2_)*512 + L*8); \
      bf16x8 b1l_ = *(const bf16x8*)(W1l + (size_t)((KT)*2 + n2_)*512 + L*8); \
      acc1_[n2_] = __builtin_amdgcn_mfma_f32_16x16x32_bf16(a1h, b1h_, acc1_[n2_], 0, 0, 0); \
      acc1_[n2_] = __builtin_amdgcn_mfma_f32_16x16x32_bf16(a1l, b1h_, acc1_[n2_], 0, 0, 0); \
      acc1_[n2_] = __builtin_amdgcn_mfma_f32_16x16x32_bf16(a1h, b1l_, acc1_[n2_], 0, 0, 0); \
    } \
    _Pragma("unroll") \
    for (int n2_ = 0; n2_ < 2; ++n2_) { \
      float bb_ = b1s[(KT)*32 + n2_*16 + r15]; \
      int col5_ = n2_*16 + r15; \
      int cb_ = col5_ >> 3; \
      _Pragma("unroll") \
      for (int q_ = 0; q_ < 4; ++q_) { \
        float z_ = acc1_[n2_][q_] + bb_; \
        int rw_ = wvid*16 + lg4*4 + q_; \
        int kcs_ = cb_ ^ ((rw_ >> 1) & 3); \
        As[BUF][rw_*32 + kcs_*8 + (col5_ & 7)] = f2bf(gelu_f(z_)); \
      } \
    } } while (0)

  // prologue: fill buffer 0 with kt=0 data (b1s is same-barrier covered)
  STAGE_BS(0, 0);
  __syncthreads();          // b1s visible for JIT
  JIT_H(0, 0);
  __syncthreads();          // As[0] visible, Bs[0] vmcnt drained

  for (int kt = 0; kt < 16; ++kt) {
    int cur = kt & 1, nxt = cur ^ 1;
    if (kt < 15) {
      STAGE_BS(kt+1, nxt);
      JIT_H(kt+1, nxt);
    }
    bf16x8 av[4], bv[8];
#pragma unroll
    for (int m = 0; m < 4; ++m) av[m] = *(const bf16x8*)&As[cur][aoff + m*512];
#pragma unroll
    for (int n = 0; n < 8; ++n) bv[n] = *(const bf16x8*)&Bs[cur][boff + n*512];
#pragma unroll
    for (int m = 0; m < 4; ++m)
#pragma unroll
      for (int n = 0; n < 8; ++n)
        acc[m][n] = __builtin_amdgcn_mfma_f32_16x16x32_bf16(av[m], bv[n], acc[m][n], 0, 0, 0);
    __syncthreads();        // reads of [cur] done; writes to [nxt] drained
  }
#undef STAGE_BS
#undef JIT_H

  // epilogue: bias + per-row mean/var over 512 cols + LN
  float b2v[8], gv[8], btv[8];
#pragma unroll
  for (int n = 0; n < 8; ++n) {
    int col = wvid*128 + n*16 + r15;
    b2v[n] = bf2[col]; gv[n] = lng[col]; btv[n] = lnb[col];
  }
  float s1[4][4], s2[4][4];
#pragma unroll
  for (int m = 0; m < 4; ++m)
#pragma unroll
    for (int r = 0; r < 4; ++r) { s1[m][r] = 0.f; s2[m][r] = 0.f; }
#pragma unroll
  for (int m = 0; m < 4; ++m)
#pragma unroll
    for (int n = 0; n < 8; ++n)
#pragma unroll
      for (int r = 0; r < 4; ++r) {
        float z = acc[m][n][r] + b2v[n];
        acc[m][n][r] = z;
        s1[m][r] += z;
        s2[m][r] = fmaf(z, z, s2[m][r]);
      }
#pragma unroll
  for (int off = 1; off < 16; off <<= 1)
#pragma unroll
    for (int m = 0; m < 4; ++m)
#pragma unroll
      for (int r = 0; r < 4; ++r) {
        s1[m][r] += __shfl_xor(s1[m][r], off, 64);
        s2[m][r] += __shfl_xor(s2[m][r], off, 64);
      }
  if (r15 == 0) {
#pragma unroll
    for (int m = 0; m < 4; ++m)
#pragma unroll
      for (int r = 0; r < 4; ++r) {
        int rw = m*16 + lg4*4 + r;
        red[rw][wvid][0] = s1[m][r];
        red[rw][wvid][1] = s2[m][r];
      }
  }
  __syncthreads();
  if (t < 64) {
    float a = red[t][0][0] + red[t][1][0] + red[t][2][0] + red[t][3][0];
    float q = red[t][0][1] + red[t][1][1] + red[t][2][1] + red[t][3][1];
    float mu = a * (1.f/512.f);
    float var = q * (1.f/512.f) - mu*mu;
    lnp[t][0] = mu;
    lnp[t][1] = rsqrtf(var + LN_EPS);
  }
  __syncthreads();
  float* ob = out + (size_t)row0*512;
#pragma unroll
  for (int m = 0; m < 4; ++m)
#pragma unroll
    for (int r = 0; r < 4; ++r) {
      int rw = m*16 + lg4*4 + r;
      float mu = lnp[rw][0], rs = lnp[rw][1];
#pragma unroll
      for (int n = 0; n < 8; ++n) {
        int col = wvid*128 + n*16 + r15;
        ob[(size_t)rw*512 + col] = fmaf((acc[m][n][r] - mu)*rs, gv[n], btv[n]);
      }
    }
}

// ---------------- kernel: desc MLP (f32) -> desc_out ----------------
__global__ __launch_bounds__(256) void k_desc(const float* descb, const float* Wd1, const float* bd1,
    const float* Wd2, const float* bd2, float* out) {
  int blk = blockIdx.x;
  int cq = blockIdx.y;
  __shared__ float ds[16][12];
  __shared__ float hd[16*512];
  int t = threadIdx.x;
  { int r = t >> 4, cc = t & 15;
    if (cc < 11) ds[r][cc] = descb[(size_t)(blk*16 + r)*16 + cc]; }
  __syncthreads();
  {
    int c0 = t, c1 = t + 256;
    float wa[11], wb[11];
#pragma unroll
    for (int k = 0; k < 11; ++k) { wa[k] = Wd1[k*512+c0]; wb[k] = Wd1[k*512+c1]; }
    float ba = bd1[c0], bb = bd1[c1];
    for (int r = 0; r < 16; ++r) {
      float a0 = ba, a1 = bb;
#pragma unroll
      for (int k = 0; k < 11; ++k) { float f = ds[r][k]; a0 = fmaf(f, wa[k], a0); a1 = fmaf(f, wb[k], a1); }
      hd[r*512+c0] = gelu_f(a0);
      hd[r*512+c1] = gelu_f(a1);
    }
  }
  __syncthreads();
  int col = cq*128 + (t & 127);
  int half = t >> 7;
  float accv[8];
  float bz = bd2[col];
#pragma unroll
  for (int r = 0; r < 8; ++r) accv[r] = bz;
  for (int k4 = 0; k4 < 128; ++k4) {
    float w0 = Wd2[(size_t)(k4*4+0)*512 + col];
    float w1 = Wd2[(size_t)(k4*4+1)*512 + col];
    float w2 = Wd2[(size_t)(k4*4+2)*512 + col];
    float w3 = Wd2[(size_t)(k4*4+3)*512 + col];
#pragma unroll
    for (int r = 0; r < 8; ++r) {
      float4 hv = *(const float4*)&hd[(half*8+r)*512 + k4*4];
      accv[r] = fmaf(hv.x, w0, fmaf(hv.y, w1, fmaf(hv.z, w2, fmaf(hv.w, w3, accv[r]))));
    }
  }
  float* ob = out + TOKENS_N;
#pragma unroll
  for (int r = 0; r < 8; ++r) {
    int grow = blk*16 + half*8 + r;
    ob[(size_t)grow*512 + col] = accv[r];
  }
}

// ---------------- launch ----------------
extern "C" void kernel_launch(void* const* d_in, const int* in_sizes, int n_in,
                              void* d_out, int out_size, void* d_ws, size_t ws_size,
                              hipStream_t stream) {
  (void)in_sizes; (void)n_in; (void)out_size; (void)ws_size;
  const float* x    = (const float*)d_in[0];
  const float* spos = (const float*)d_in[1];
  const void*  mask = d_in[2];
  const float* Wf1  = (const float*)d_in[3];
  const float* bf1  = (const float*)d_in[4];
  const float* Wf2  = (const float*)d_in[5];
  const float* bf2  = (const float*)d_in[6];
  const float* lng  = (const float*)d_in[7];
  const float* lnb  = (const float*)d_in[8];
  const float* Wd1  = (const float*)d_in[9];
  const float* bd1  = (const float*)d_in[10];
  const float* Wd2  = (const float*)d_in[11];
  const float* bd2  = (const float*)d_in[12];
  char* ws = (char*)d_ws;
  float*          bpg   = (float*)(ws + BP_OFF);
  unsigned short* FBh   = (unsigned short*)(ws + BTH_OFF);
  unsigned short* FBl   = (unsigned short*)(ws + BTL_OFF);
  float*          feat  = (float*)(ws + FEAT_OFF);
  unsigned short* W1h   = (unsigned short*)(ws + W1H_OFF);
  unsigned short* W1l   = (unsigned short*)(ws + W1L_OFF);
  unsigned short* Wt    = (unsigned short*)(ws + WT_OFF);
  float*          descb = (float*)(ws + DSC_OFF);
  float*          maskf = (float*)(ws + MSK_OFF);
  float*          regm  = (float*)(ws + REG_OFF);
  float*          cnts  = (float*)(ws + CNT_OFF);
  float*          sup   = (float*)(ws + SUP_OFF);
  float*          out   = (float*)d_out;

  hipLaunchKernelGGL(k_setup,  dim3(1),      dim3(1024), 0, stream, mask, spos, maskf, regm, cnts, sup);
  hipLaunchKernelGGL(k_wt,     dim3(8,8),    dim3(256),  0, stream, Wf2, Wt);
  hipLaunchKernelGGL(k_w1,     dim3(64),     dim3(256),  0, stream, Wf1, W1h, W1l);
  hipLaunchKernelGGL(k_twid,   dim3(128),    dim3(256),  0, stream, FBh, FBl);
  hipLaunchKernelGGL(k_dft,    dim3(64,16),  dim3(256),  0, stream, x, maskf, FBh, FBl, bpg);
  hipLaunchKernelGGL(k_feat2,  dim3(59,16),  dim3(64),   0, stream, bpg, spos, maskf, regm, cnts, sup, feat, descb);
  hipLaunchKernelGGL(k_tok,    dim3(944),    dim3(256),  0, stream, feat, W1h, W1l, bf1, Wt, bf2, lng, lnb, out);
  hipLaunchKernelGGL(k_desc,   dim3(59,4),   dim3(256),  0, stream, descb, Wd1, bd1, Wd2, bd2, out);
}